// Round 1
// baseline (102.245 us; speedup 1.0000x reference)
//
#include <hip/hip_runtime.h>
#include <hip/hip_bf16.h>
#include <math.h>

// VectorQuantizer: z [65536 x 64] fp32, codebook [1024 x 64] fp32.
// dist = (||z||^2 - 2 z.e) + ||e||^2, argmin_k, first-occurrence ties.
// Numerics identical to R4-R8 (absmax 0): exact np pairwise sumsq for S/cn;
// d via f16 split-2 3-pass MFMA; dist = (S - 2d) + cn explicit __f*_rn;
// (val, lowest-k) reduce. MFMA accumulation order preserved bit-exactly.
//
// R8 post-mortem: MfmaUtil 23 / VALUBusy 30 / Occ 17 -- no pipe half-busy.
// Per-stage the 4-deep dependent aC MFMA chain was read by the epilogue
// ~30cy after issue (~100cy stall), and each LOADB->MFMA pair stalled on
// ~120cy LDS latency; barrier-synced waves sit in-phase so pipes alternate
// idle. R9: 2-slot software pipeline per tile:
//   PREFETCH(t+1); LOADB(A,ct0); LOADB(B,ct1);
//   EPI(B: prev ct3)   <- 112cy VALU covers both LOADBs' LDS latency
//   MFMA(A,ct0); LOADB(A,ct2); MFMA(B,ct1); LOADB(B,ct3);
//   EPI(A,ct0); MFMA(A,ct2); EPI(B,ct1); MFMA(B,ct3); EPI(A,ct2); barrier
// Pending ct3 epilogue slides to next tile top. cn kept in 4 rotating regs
// (cnv3 survives the barrier; only WAR hazard of the 2-slot scheme).
// rt0/rt1 MFMA chains issue-interleaved (independent accs feed the pipe).

#define D      64
#define K      1024
#define BLOCK  256

typedef _Float16 half8_t __attribute__((ext_vector_type(8)));
typedef float    floatx4 __attribute__((ext_vector_type(4)));

// ws layout
#define WS_CN_OFF    0            // float[1024]         (4 KB)
#define WS_EF_OFF    4096         // _Float16[131072]    (256 KB)
// per 64-code tile t (16 KB): frag (spl,ch,ct) at half-offset
//   t*8192 + 512*((spl*2+ch)*4+ct) + 8*lane

__device__ __forceinline__ void gld_lds16(const void* g, void* l) {
    __builtin_amdgcn_global_load_lds(
        (const __attribute__((address_space(1))) void*)g,
        (__attribute__((address_space(3))) void*)l, 16, 0, 0);
}

// numpy pairwise sumsq (n=64): 8 stride-8 accs of fl(x^2), tree combine.
__device__ __forceinline__ float np_sumsq64_p(const float* __restrict__ x) {
    float r[8];
    {
        float4 v0 = *(const float4*)(x);
        float4 v1 = *(const float4*)(x + 4);
        r[0] = __fmul_rn(v0.x, v0.x); r[1] = __fmul_rn(v0.y, v0.y);
        r[2] = __fmul_rn(v0.z, v0.z); r[3] = __fmul_rn(v0.w, v0.w);
        r[4] = __fmul_rn(v1.x, v1.x); r[5] = __fmul_rn(v1.y, v1.y);
        r[6] = __fmul_rn(v1.z, v1.z); r[7] = __fmul_rn(v1.w, v1.w);
    }
#pragma unroll
    for (int i = 8; i < 64; i += 8) {
        float4 v0 = *(const float4*)(x + i);
        float4 v1 = *(const float4*)(x + i + 4);
        r[0] = __fadd_rn(r[0], __fmul_rn(v0.x, v0.x));
        r[1] = __fadd_rn(r[1], __fmul_rn(v0.y, v0.y));
        r[2] = __fadd_rn(r[2], __fmul_rn(v0.z, v0.z));
        r[3] = __fadd_rn(r[3], __fmul_rn(v0.w, v0.w));
        r[4] = __fadd_rn(r[4], __fmul_rn(v1.x, v1.x));
        r[5] = __fadd_rn(r[5], __fmul_rn(v1.y, v1.y));
        r[6] = __fadd_rn(r[6], __fmul_rn(v1.z, v1.z));
        r[7] = __fadd_rn(r[7], __fmul_rn(v1.w, v1.w));
    }
    return __fadd_rn(__fadd_rn(__fadd_rn(r[0], r[1]), __fadd_rn(r[2], r[3])),
                     __fadd_rn(__fadd_rn(r[4], r[5]), __fadd_rn(r[6], r[7])));
}

// ---- precompute: code norms + f16 split-2 B-frags in MFMA lane order ----
__global__ void vq_pre(const float* __restrict__ cb, float* __restrict__ cn,
                       _Float16* __restrict__ ef) {
    const int k = blockIdx.x * 64 + threadIdx.x;
    if (k >= K) return;
    cn[k] = np_sumsq64_p(cb + (long)k * D);
    const int t = k >> 6, ct = (k >> 4) & 3, l16 = k & 15;
#pragma unroll
    for (int ch = 0; ch < 2; ++ch)
#pragma unroll
        for (int quad = 0; quad < 4; ++quad) {
            const float* p = cb + (long)k * D + ch * 32 + quad * 8;
            half8_t h1, h2;
#pragma unroll
            for (int j = 0; j < 8; ++j) {
                float x10 = __fmul_rn(p[j], 1024.0f);        // exact pow2 scale
                _Float16 g1 = (_Float16)x10;
                h1[j] = g1;
                h2[j] = (_Float16)(__fmul_rn(__fsub_rn(x10, (float)g1), 2048.0f));
            }
            const int base = t * 8192 + 128 * quad + 8 * l16;
            *(half8_t*)(ef + base + 512 * (ch * 4 + ct))       = h1;
            *(half8_t*)(ef + base + 512 * ((2 + ch) * 4 + ct)) = h2;
        }
}

// ---- main: 128 rows x ALL 1024 codes per 4-wave block; fused outputs ----
__global__ __launch_bounds__(BLOCK, 2) void vq_main(
    const float* __restrict__ z, const float* __restrict__ cb,
    const _Float16* __restrict__ ef, const float* __restrict__ cn,
    float* __restrict__ zq, float* __restrict__ idx_out) {
    // zf (128 x 68 f32 = 34816 B) unioned with two 16 KB frag buffers
    __shared__ __align__(16) char smem[34816];
    __shared__ float sS[128];
    __shared__ float sCn[K];
    __shared__ int   sBi[128];
    float*    zf   = (float*)smem;
    _Float16* bufs = (_Float16*)smem;     // buf b at bufs + b*8192

    const int tid  = threadIdx.x;
    const int lane = tid & 63;
    const int wv   = tid >> 6;
    const int quad = lane >> 4;
    const int l16  = lane & 15;
    const long rowbase = (long)blockIdx.x * 128;

    // ---- stage z (coalesced) + all code norms ----
    const float4* gz = (const float4*)(z + rowbase * D);
#pragma unroll
    for (int i = 0; i < 8; ++i) {
        int idx4 = i * BLOCK + tid;
        int r = idx4 >> 4, j = idx4 & 15;
        *(float4*)(zf + r * 68 + j * 4) = gz[idx4];
    }
#pragma unroll
    for (int i = 0; i < 4; ++i) sCn[i * 256 + tid] = cn[i * 256 + tid];
    __syncthreads();

    // row norms (exact np chain)
    if (tid < 128) sS[tid] = np_sumsq64_p(zf + tid * 68);

    // A-frags: register-resident f16 splits; wave wv -> rows wv*32 .. +31
    half8_t a1[2][2], a2[2][2];
#pragma unroll
    for (int rt = 0; rt < 2; ++rt) {
        const int row = wv * 32 + rt * 16 + l16;
#pragma unroll
        for (int ch = 0; ch < 2; ++ch) {
            const float* p = zf + row * 68 + ch * 32 + quad * 8;
            float4 f0 = *(const float4*)(p);
            float4 f1 = *(const float4*)(p + 4);
            float xs[8] = {f0.x, f0.y, f0.z, f0.w, f1.x, f1.y, f1.z, f1.w};
#pragma unroll
            for (int j = 0; j < 8; ++j) {
                _Float16 h1 = (_Float16)xs[j];
                a1[rt][ch][j] = h1;
                a2[rt][ch][j] =
                    (_Float16)(__fmul_rn(__fsub_rn(xs[j], (float)h1), 2048.0f));
            }
        }
    }
    __syncthreads();   // all zf reads done (sS + frags); sS visible

    float myS[2][4];
#pragma unroll
    for (int rt = 0; rt < 2; ++rt)
#pragma unroll
        for (int r = 0; r < 4; ++r)
            myS[rt][r] = sS[wv * 32 + rt * 16 + quad * 4 + r];

    float bv[2][4];
    int   bi[2][4];
#pragma unroll
    for (int rt = 0; rt < 2; ++rt)
#pragma unroll
        for (int r = 0; r < 4; ++r) { bv[rt][r] = INFINITY; bi[rt][r] = 0; }

    const char* eb = (const char*)ef;

    // stage tile 0 (async DMA: wave wv copies its 4 KB quarter)
    {
        const char* g = eb + wv * 4096 + lane * 16;
        char* l = (char*)bufs + wv * 4096;       // wave-uniform dest base
#pragma unroll
        for (int i = 0; i < 4; ++i) gld_lds16(g + i * 1024, l + i * 1024);
    }

    // ---- pipeline register state ----
    half8_t b1A[2], b2A[2], b1B[2], b2B[2];
    floatx4 aMA0, aMA1, aCA0, aCA1, aMB0, aMB1, aCB0, aCB1;
    float cnv0, cnv1, cnv2, cnv3;

    // pending-slot neutral init: dist evaluates to (S-(-INF))+0 = +INF,
    // never selected (strict < in-loop); kgbase for t=0 is -16, harmless.
    {
        const floatx4 NI = {-INFINITY, -INFINITY, -INFINITY, -INFINITY};
        const floatx4 Z4 = {0.f, 0.f, 0.f, 0.f};
        aMB0 = NI; aMB1 = NI; aCB0 = Z4; aCB1 = Z4;
        cnv3 = 0.f;
    }

#define LOADB(b1_, b2_, cnv_, t_, ct_) do {                                   \
        const _Float16* tb_ = bufs + ((t_) & 1) * 8192 + 8 * lane;            \
        b1_[0] = *(const half8_t*)(tb_ + 512 * (0 * 4 + (ct_)));              \
        b1_[1] = *(const half8_t*)(tb_ + 512 * (1 * 4 + (ct_)));              \
        b2_[0] = *(const half8_t*)(tb_ + 512 * (2 * 4 + (ct_)));              \
        b2_[1] = *(const half8_t*)(tb_ + 512 * (3 * 4 + (ct_)));              \
        cnv_ = sCn[(t_) * 64 + (ct_) * 16 + l16];                             \
    } while (0)

// 12 MFMAs, rt0/rt1 chains interleaved (independent accs back-to-back).
// Accumulation order per element identical to R8: aM = a1b1(ch0)+a1b1(ch1);
// aC = a1b2(ch0)+a1b2(ch1)+a2b1(ch0)+a2b1(ch1).
#define MFMAG(aM0_, aM1_, aC0_, aC1_, b1_, b2_) do {                          \
        const floatx4 Z4_ = {0.f, 0.f, 0.f, 0.f};                             \
        aM0_ = __builtin_amdgcn_mfma_f32_16x16x32_f16(a1[0][0], b1_[0], Z4_, 0, 0, 0); \
        aM1_ = __builtin_amdgcn_mfma_f32_16x16x32_f16(a1[1][0], b1_[0], Z4_, 0, 0, 0); \
        aM0_ = __builtin_amdgcn_mfma_f32_16x16x32_f16(a1[0][1], b1_[1], aM0_, 0, 0, 0); \
        aM1_ = __builtin_amdgcn_mfma_f32_16x16x32_f16(a1[1][1], b1_[1], aM1_, 0, 0, 0); \
        aC0_ = __builtin_amdgcn_mfma_f32_16x16x32_f16(a1[0][0], b2_[0], Z4_, 0, 0, 0); \
        aC1_ = __builtin_amdgcn_mfma_f32_16x16x32_f16(a1[1][0], b2_[0], Z4_, 0, 0, 0); \
        aC0_ = __builtin_amdgcn_mfma_f32_16x16x32_f16(a1[0][1], b2_[1], aC0_, 0, 0, 0); \
        aC1_ = __builtin_amdgcn_mfma_f32_16x16x32_f16(a1[1][1], b2_[1], aC1_, 0, 0, 0); \
        aC0_ = __builtin_amdgcn_mfma_f32_16x16x32_f16(a2[0][0], b1_[0], aC0_, 0, 0, 0); \
        aC1_ = __builtin_amdgcn_mfma_f32_16x16x32_f16(a2[1][0], b1_[0], aC1_, 0, 0, 0); \
        aC0_ = __builtin_amdgcn_mfma_f32_16x16x32_f16(a2[0][1], b1_[1], aC0_, 0, 0, 0); \
        aC1_ = __builtin_amdgcn_mfma_f32_16x16x32_f16(a2[1][1], b1_[1], aC1_, 0, 0, 0); \
    } while (0)

// exact dist chain, unchanged: ds=fma(aC,2^-11,aM); t2=ds*2^-9 (exact pow2);
// dist=(S-t2)+cn; strict < keeps first occurrence.
#define EPI(aM0_, aM1_, aC0_, aC1_, cnv_, kb_) do {                           \
        const int kg_ = (kb_) + l16;                                          \
        _Pragma("unroll")                                                     \
        for (int r = 0; r < 4; ++r) {                                         \
            float ds0_ = fmaf(aC0_[r], 0x1p-11f, aM0_[r]);                    \
            float d0_ = __fadd_rn(__fsub_rn(myS[0][r],                        \
                            __fmul_rn(ds0_, 0x1p-9f)), cnv_);                 \
            if (d0_ < bv[0][r]) { bv[0][r] = d0_; bi[0][r] = kg_; }           \
            float ds1_ = fmaf(aC1_[r], 0x1p-11f, aM1_[r]);                    \
            float d1_ = __fadd_rn(__fsub_rn(myS[1][r],                        \
                            __fmul_rn(ds1_, 0x1p-9f)), cnv_);                 \
            if (d1_ < bv[1][r]) { bv[1][r] = d1_; bi[1][r] = kg_; }           \
        }                                                                     \
    } while (0)

    __syncthreads();   // tile 0 staged (barrier drains vmcnt)

#pragma unroll 2
    for (int t = 0; t < 16; ++t) {
        // prefetch tile t+1 into the other buffer (async, lands by barrier)
        if (t < 15) {
            const char* g = eb + (t + 1) * 16384 + wv * 4096 + lane * 16;
            char* l = (char*)bufs + ((t + 1) & 1) * 16384 + wv * 4096;
#pragma unroll
            for (int i = 0; i < 4; ++i) gld_lds16(g + i * 1024, l + i * 1024);
        }

        LOADB(b1A, b2A, cnv0, t, 0);
        LOADB(b1B, b2B, cnv1, t, 1);
        // pending epilogue (t-1, ct3): 112cy VALU under the LOADBs' latency
        EPI(aMB0, aMB1, aCB0, aCB1, cnv3, (t - 1) * 64 + 48);
        MFMAG(aMA0, aMA1, aCA0, aCA1, b1A, b2A);            // ct0
        LOADB(b1A, b2A, cnv2, t, 2);                        // WAR ok post-issue
        MFMAG(aMB0, aMB1, aCB0, aCB1, b1B, b2B);            // ct1
        LOADB(b1B, b2B, cnv3, t, 3);
        EPI(aMA0, aMA1, aCA0, aCA1, cnv0, t * 64 + 0);      // ct0
        MFMAG(aMA0, aMA1, aCA0, aCA1, b1A, b2A);            // ct2
        EPI(aMB0, aMB1, aCB0, aCB1, cnv1, t * 64 + 16);     // ct1
        MFMAG(aMB0, aMB1, aCB0, aCB1, b1B, b2B);            // ct3
        EPI(aMA0, aMA1, aCA0, aCA1, cnv2, t * 64 + 32);     // ct2
        __syncthreads();  // t+1 staged; cur reads done before t+2 overwrites
    }
    // drain the pipeline: (t=15, ct3)
    EPI(aMB0, aMB1, aCB0, aCB1, cnv3, 15 * 64 + 48);

#undef LOADB
#undef MFMAG
#undef EPI

    // reduce over the 16 code-columns; (val, lowest index) = first occurrence
#pragma unroll
    for (int rt = 0; rt < 2; ++rt)
#pragma unroll
        for (int r = 0; r < 4; ++r) {
            float v = bv[rt][r];
            int   x = bi[rt][r];
#pragma unroll
            for (int off = 1; off <= 8; off <<= 1) {
                float ov = __shfl_xor(v, off);
                int   ox = __shfl_xor(x, off);
                if (ov < v || (ov == v && ox < x)) { v = ov; x = ox; }
            }
            if (l16 == 0) {
                const int rl = wv * 32 + rt * 16 + quad * 4 + r;
                sBi[rl] = x;
                idx_out[rowbase + rl] = (float)x;
            }
        }
    __syncthreads();

    // ---- zq gather: zq[row] = cb[bi[row]] (cb L2-hot, coalesced writes) ----
    const float4* cb4 = (const float4*)cb;
    float4* zq4 = (float4*)(zq + rowbase * D);
#pragma unroll
    for (int i = 0; i < 8; ++i) {
        int idx4 = i * BLOCK + tid;
        int r = idx4 >> 4, j = idx4 & 15;
        zq4[idx4] = cb4[(long)sBi[r] * 16 + j];
    }
}

extern "C" void kernel_launch(void* const* d_in, const int* in_sizes, int n_in,
                              void* d_out, int out_size, void* d_ws, size_t ws_size,
                              hipStream_t stream) {
    const float* z  = (const float*)d_in[0];
    const float* cb = (const float*)d_in[1];

    const int n_rows = in_sizes[0] / D;                 // 65536
    float* zq      = (float*)d_out;
    float* idx_out = zq + (long)n_rows * D;

    float*    ws_cn = (float*)((char*)d_ws + WS_CN_OFF);
    _Float16* ws_ef = (_Float16*)((char*)d_ws + WS_EF_OFF);

    vq_pre<<<K / 64, 64, 0, stream>>>(cb, ws_cn, ws_ef);
    vq_main<<<n_rows / 128, BLOCK, 0, stream>>>(z, cb, ws_ef, ws_cn, zq, idx_out);
}